// Round 4
// baseline (499.418 us; speedup 1.0000x reference)
//
#include <hip/hip_runtime.h>

#define EPS 1e-5f

typedef __attribute__((ext_vector_type(8))) short short8;
typedef __attribute__((ext_vector_type(4))) float f32x4;

// ---- ws layout ----
// shorts [0, 131072)      : shW frags, idx = (kq*256 + n)*8 + j, k = kq*8+j (BN0 scale folded)
// shorts [131072, 180224) : stW frags, idx = 131072 + s*16384 + (kq*128 + n')*8 + j,
//                           actual col n = n' (<64) or n'+64
// floats (on d_ws as float*):
#define C1_OFF   90112
#define C2_OFF   90368
#define STC1_OFF 90624
#define STC2_OFF 91392

__device__ inline unsigned short f2bf(float f) {
  unsigned u = __builtin_bit_cast(unsigned, f);
  u += 0x7FFFu + ((u >> 16) & 1u);
  return (unsigned short)(u >> 16);
}

__device__ inline short8 cvt8(f32x4 a, f32x4 b) {
  short8 r;
  r[0] = (short)f2bf(a[0]); r[1] = (short)f2bf(a[1]);
  r[2] = (short)f2bf(a[2]); r[3] = (short)f2bf(a[3]);
  r[4] = (short)f2bf(b[0]); r[5] = (short)f2bf(b[1]);
  r[6] = (short)f2bf(b[2]); r[7] = (short)f2bf(b[3]);
  return r;
}

// ---------------- prep kernels ----------------
__global__ void prep_w(const float* __restrict__ shW, const float* __restrict__ stW,
                       const float* __restrict__ bn0_g, const float* __restrict__ bn0_v,
                       unsigned short* __restrict__ ws) {
  int t = blockIdx.x * 256 + threadIdx.x;
  if (t < 16384) {
    int kq = t >> 8, n = t & 255;
    short8 o;
#pragma unroll
    for (int j = 0; j < 8; ++j) {
      int k = kq * 8 + j;
      float scale = bn0_g[k] * rsqrtf(bn0_v[k] + EPS);
      o[j] = (short)f2bf(shW[k * 256 + n] * scale);
    }
    *(short8*)&ws[t * 8] = o;
  } else if (t < 16384 + 6144) {
    int r = t - 16384;
    int s = r >> 11, rem = r & 2047;
    int kq = rem >> 7, np = rem & 127;
    int n = np < 64 ? np : np + 64;
    short8 o;
#pragma unroll
    for (int j = 0; j < 8; ++j) o[j] = (short)f2bf(stW[(s * 128 + kq * 8 + j) * 256 + n]);
    *(short8*)&ws[131072 + r * 8] = o;
  }
}

__global__ void prep_b(const float* __restrict__ shW,
                       const float* __restrict__ bn0_g, const float* __restrict__ bn0_b,
                       const float* __restrict__ bn0_m, const float* __restrict__ bn0_v,
                       const float* __restrict__ sh_g, const float* __restrict__ sh_b,
                       const float* __restrict__ sh_m, const float* __restrict__ sh_v,
                       const float* __restrict__ st_g, const float* __restrict__ st_b,
                       const float* __restrict__ st_m, const float* __restrict__ st_v,
                       float* __restrict__ wsf) {
  const int n = blockIdx.x, t = threadIdx.x;
  float part = 0.f;
#pragma unroll
  for (int kk = 0; kk < 2; ++kk) {
    int k = t + kk * 256;
    float sc = bn0_g[k] * rsqrtf(bn0_v[k] + EPS);
    part += (bn0_b[k] - bn0_m[k] * sc) * shW[k * 256 + n];
  }
#pragma unroll
  for (int m = 1; m < 64; m <<= 1) part += __shfl_xor(part, m);
  __shared__ float wsum[4];
  if ((t & 63) == 0) wsum[t >> 6] = part;
  __syncthreads();
  if (t == 0) {
    float bias = wsum[0] + wsum[1] + wsum[2] + wsum[3];
    float c1 = sh_g[n] * rsqrtf(sh_v[n] + EPS);
    wsf[C1_OFF + n] = c1;
    wsf[C2_OFF + n] = (bias - sh_m[n]) * c1 + sh_b[n];
#pragma unroll
    for (int s = 0; s < 3; ++s) {
      float a = st_g[s * 256 + n] * rsqrtf(st_v[s * 256 + n] + EPS);
      wsf[STC1_OFF + s * 256 + n] = a;
      wsf[STC2_OFF + s * 256 + n] = st_b[s * 256 + n] - st_m[s * 256 + n] * a;
    }
  }
}

// ---------------- main fused kernel ----------------
// 2048 blocks x 256 threads, 64 rows/block. 2x2 wave tiling: wave (wm,wn) owns
// rows [wm*32, wm*32+32) and value cols [wn*64,..)+gates(+128) -> GLU in-lane.
// x prefetched 2 steps deep; cvt-wait drains only 2-iter-old loads.
__global__ __launch_bounds__(256, 3) void tabnet_main(
    const float* __restrict__ x, const unsigned short* __restrict__ wsu,
    const float* __restrict__ wsf, const float* __restrict__ fW,
    const float* __restrict__ fb, float* __restrict__ out) {

  __shared__ __align__(16) unsigned short lds_sh[16 * 64 * 8];  // 16 KB, sh A-frags
  __shared__ float lds_red[64][2][2];                           // 1 KB

  const int tid = threadIdx.x;
  const int wave = tid >> 6, lane = tid & 63;
  const int q = lane >> 4, l15 = lane & 15;
  const int wm = wave >> 1, wn = wave & 1;
  const long row0 = (long)blockIdx.x * 64;

  const float* xr0 = x + (row0 + wm * 32 + l15) * 512 + q * 8;
  const float* xr1 = xr0 + 16 * 512;

  f32x4 acc[2][8];
#pragma unroll
  for (int a = 0; a < 2; ++a)
#pragma unroll
    for (int b = 0; b < 8; ++b) acc[a][b] = (f32x4)0.f;

  const int ncv = wn * 64 + l15;  // value col base (+nt*16); gate = +128

  // ---- Phase 1: K=512 as 16 steps of 32; x pipelined 2 steps deep ----
  f32x4 xs[2][2][2];  // [parity][mt][half]
#pragma unroll
  for (int d = 0; d < 2; ++d) {
    xs[d][0][0] = *(const f32x4*)(xr0 + d * 32);
    xs[d][0][1] = *(const f32x4*)(xr0 + d * 32 + 4);
    xs[d][1][0] = *(const f32x4*)(xr1 + d * 32);
    xs[d][1][1] = *(const f32x4*)(xr1 + d * 32 + 4);
  }
  for (int st = 0; st < 16; ++st) {
    const unsigned short* wb = wsu + (st * 4 + q) * 2048;
    short8 bf[8];
#pragma unroll
    for (int nt = 0; nt < 4; ++nt) {
      bf[nt]     = *(const short8*)&wb[(ncv + nt * 16) * 8];
      bf[nt + 4] = *(const short8*)&wb[(ncv + nt * 16 + 128) * 8];
    }
    const int cur = st & 1;
    short8 af[2];
    af[0] = cvt8(xs[cur][0][0], xs[cur][0][1]);  // waits only x(st), issued 2 iters ago
    af[1] = cvt8(xs[cur][1][0], xs[cur][1][1]);
    if (st < 14) {
      const int o = (st + 2) * 32;
      xs[cur][0][0] = *(const f32x4*)(xr0 + o);
      xs[cur][0][1] = *(const f32x4*)(xr0 + o + 4);
      xs[cur][1][0] = *(const f32x4*)(xr1 + o);
      xs[cur][1][1] = *(const f32x4*)(xr1 + o + 4);
    }
#pragma unroll
    for (int nt = 0; nt < 8; ++nt)
#pragma unroll
      for (int mt = 0; mt < 2; ++mt)
        acc[mt][nt] =
            __builtin_amdgcn_mfma_f32_16x16x32_bf16(af[mt], bf[nt], acc[mt][nt], 0, 0, 0);
  }

  // ---- Phase-1 epilogue: BN + GLU in registers -> lds_sh (A-frag layout) ----
#pragma unroll
  for (int nt = 0; nt < 4; ++nt) {
    const int c = wn * 64 + nt * 16 + l15;  // sh col in [0,128)
    const float v1 = wsf[C1_OFF + c], v2 = wsf[C2_OFF + c];
    const float g1 = wsf[C1_OFF + c + 128], g2 = wsf[C2_OFF + c + 128];
#pragma unroll
    for (int mt = 0; mt < 2; ++mt)
#pragma unroll
      for (int r = 0; r < 4; ++r) {
        float y1 = acc[mt][nt][r] * v1 + v2;
        float y2 = acc[mt][nt + 4][r] * g1 + g2;
        float sg = __builtin_amdgcn_rcpf(1.f + __expf(-y2));
        int row = wm * 32 + mt * 16 + 4 * q + r;
        lds_sh[((c >> 3) * 64 + row) * 8 + (c & 7)] = f2bf(y1 * sg);
      }
  }
  __syncthreads();

  // ---- Phase 2: 3 steps, K=128; A from lds_sh, B direct from global (L2-hot) ----
  float agg[2][2][4];
#pragma unroll
  for (int a = 0; a < 2; ++a)
#pragma unroll
    for (int b = 0; b < 2; ++b)
#pragma unroll
      for (int r = 0; r < 4; ++r) agg[a][b][r] = 0.f;

  for (int s = 0; s < 3; ++s) {
    const unsigned short* wb = wsu + 131072 + s * 16384;
    f32x4 acc2[2][4];
#pragma unroll
    for (int a = 0; a < 2; ++a)
#pragma unroll
      for (int b = 0; b < 4; ++b) acc2[a][b] = (f32x4)0.f;
#pragma unroll
    for (int ks = 0; ks < 4; ++ks) {
      const int kq = ks * 4 + q;
      short8 bs[4];
#pragma unroll
      for (int j = 0; j < 2; ++j) {
        bs[j]     = *(const short8*)&wb[(kq * 128 + wn * 32 + j * 16 + l15) * 8];
        bs[j + 2] = *(const short8*)&wb[(kq * 128 + 64 + wn * 32 + j * 16 + l15) * 8];
      }
      short8 af[2];
#pragma unroll
      for (int mt = 0; mt < 2; ++mt)
        af[mt] = *(const short8*)&lds_sh[(kq * 64 + wm * 32 + mt * 16 + l15) * 8];
#pragma unroll
      for (int j = 0; j < 4; ++j)
#pragma unroll
        for (int mt = 0; mt < 2; ++mt)
          acc2[mt][j] =
              __builtin_amdgcn_mfma_f32_16x16x32_bf16(af[mt], bs[j], acc2[mt][j], 0, 0, 0);
    }
#pragma unroll
    for (int j = 0; j < 2; ++j) {
      const int n1 = wn * 32 + j * 16 + l15;  // value col in [0,64)
      const float a1 = wsf[STC1_OFF + s * 256 + n1], b1 = wsf[STC2_OFF + s * 256 + n1];
      const float a2 = wsf[STC1_OFF + s * 256 + n1 + 128], b2 = wsf[STC2_OFF + s * 256 + n1 + 128];
#pragma unroll
      for (int mt = 0; mt < 2; ++mt)
#pragma unroll
        for (int r = 0; r < 4; ++r) {
          float y1 = acc2[mt][j][r] * a1 + b1;
          float y2 = acc2[mt][j + 2][r] * a2 + b2;
          agg[mt][j][r] += y1 * __builtin_amdgcn_rcpf(1.f + __expf(-y2));
        }
    }
  }

  // ---- Final: out = agg @ fW + fb ----
  {
#pragma unroll
    for (int mt = 0; mt < 2; ++mt)
#pragma unroll
      for (int r = 0; r < 4; ++r) {
        float p0 = 0.f, p1 = 0.f;
#pragma unroll
        for (int j = 0; j < 2; ++j) {
          const int c = wn * 32 + j * 16 + l15;
          p0 += agg[mt][j][r] * fW[c * 2];
          p1 += agg[mt][j][r] * fW[c * 2 + 1];
        }
#pragma unroll
        for (int m = 1; m < 16; m <<= 1) {
          p0 += __shfl_xor(p0, m);
          p1 += __shfl_xor(p1, m);
        }
        if (l15 == 0) {
          int row = wm * 32 + mt * 16 + 4 * q + r;
          lds_red[row][0][wn] = p0;
          lds_red[row][1][wn] = p1;
        }
      }
  }
  __syncthreads();
  if (tid < 128) {
    int row = tid >> 1, o = tid & 1;
    out[(row0 + row) * 2 + o] = fb[o] + lds_red[row][o][0] + lds_red[row][o][1];
  }
}

extern "C" void kernel_launch(void* const* d_in, const int* in_sizes, int n_in,
                              void* d_out, int out_size, void* d_ws, size_t ws_size,
                              hipStream_t stream) {
  const float* x     = (const float*)d_in[0];
  const float* bn0_g = (const float*)d_in[1];
  const float* bn0_b = (const float*)d_in[2];
  const float* bn0_m = (const float*)d_in[3];
  const float* bn0_v = (const float*)d_in[4];
  const float* shW   = (const float*)d_in[5];
  const float* sh_g  = (const float*)d_in[6];
  const float* sh_b  = (const float*)d_in[7];
  const float* sh_m  = (const float*)d_in[8];
  const float* sh_v  = (const float*)d_in[9];
  const float* stW   = (const float*)d_in[10];
  const float* st_g  = (const float*)d_in[11];
  const float* st_b  = (const float*)d_in[12];
  const float* st_m  = (const float*)d_in[13];
  const float* st_v  = (const float*)d_in[14];
  // d_in[15..19] = atW, at_g, at_b, at_m, at_v : dead code (never feeds output)
  const float* fW    = (const float*)d_in[20];
  const float* fb    = (const float*)d_in[21];

  unsigned short* wsu = (unsigned short*)d_ws;
  float* wsf = (float*)d_ws;

  prep_w<<<88, 256, 0, stream>>>(shW, stW, bn0_g, bn0_v, wsu);
  prep_b<<<256, 256, 0, stream>>>(shW, bn0_g, bn0_b, bn0_m, bn0_v, sh_g, sh_b, sh_m,
                                  sh_v, st_g, st_b, st_m, st_v, wsf);
  tabnet_main<<<2048, 256, 0, stream>>>(x, wsu, wsf, fW, fb, (float*)d_out);
}

// Round 5
// 487.164 us; speedup vs baseline: 1.0252x; 1.0252x over previous
//
#include <hip/hip_runtime.h>

#define EPS 1e-5f

typedef __attribute__((ext_vector_type(8))) short short8;
typedef __attribute__((ext_vector_type(4))) float f32x4;

// ---- ws layout ----
// shorts [0, 131072)      : shW frags, idx = (kq*256 + n)*8 + j, k = kq*8+j (BN0 scale folded)
// shorts [131072, 180224) : stW frags, idx = 131072 + s*16384 + (kq*128 + n')*8 + j,
//                           actual col n = n' (<64) or n'+64
// floats (on d_ws as float*):
#define C1_OFF   90112
#define C2_OFF   90368
#define STC1_OFF 90624
#define STC2_OFF 91392

#define XSTRIDE 520  // shorts per LDS x row: 512 + 8 pad -> banks spread on read AND write

__device__ inline unsigned short f2bf(float f) {
  unsigned u = __builtin_bit_cast(unsigned, f);
  u += 0x7FFFu + ((u >> 16) & 1u);
  return (unsigned short)(u >> 16);
}

__device__ inline short8 cvt8(f32x4 a, f32x4 b) {
  short8 r;
  r[0] = (short)f2bf(a[0]); r[1] = (short)f2bf(a[1]);
  r[2] = (short)f2bf(a[2]); r[3] = (short)f2bf(a[3]);
  r[4] = (short)f2bf(b[0]); r[5] = (short)f2bf(b[1]);
  r[6] = (short)f2bf(b[2]); r[7] = (short)f2bf(b[3]);
  return r;
}

// ---------------- prep kernels ----------------
__global__ void prep_w(const float* __restrict__ shW, const float* __restrict__ stW,
                       const float* __restrict__ bn0_g, const float* __restrict__ bn0_v,
                       unsigned short* __restrict__ ws) {
  int t = blockIdx.x * 256 + threadIdx.x;
  if (t < 16384) {
    int kq = t >> 8, n = t & 255;
    short8 o;
#pragma unroll
    for (int j = 0; j < 8; ++j) {
      int k = kq * 8 + j;
      float scale = bn0_g[k] * rsqrtf(bn0_v[k] + EPS);
      o[j] = (short)f2bf(shW[k * 256 + n] * scale);
    }
    *(short8*)&ws[t * 8] = o;
  } else if (t < 16384 + 6144) {
    int r = t - 16384;
    int s = r >> 11, rem = r & 2047;
    int kq = rem >> 7, np = rem & 127;
    int n = np < 64 ? np : np + 64;
    short8 o;
#pragma unroll
    for (int j = 0; j < 8; ++j) o[j] = (short)f2bf(stW[(s * 128 + kq * 8 + j) * 256 + n]);
    *(short8*)&ws[131072 + r * 8] = o;
  }
}

__global__ void prep_b(const float* __restrict__ shW,
                       const float* __restrict__ bn0_g, const float* __restrict__ bn0_b,
                       const float* __restrict__ bn0_m, const float* __restrict__ bn0_v,
                       const float* __restrict__ sh_g, const float* __restrict__ sh_b,
                       const float* __restrict__ sh_m, const float* __restrict__ sh_v,
                       const float* __restrict__ st_g, const float* __restrict__ st_b,
                       const float* __restrict__ st_m, const float* __restrict__ st_v,
                       float* __restrict__ wsf) {
  const int n = blockIdx.x, t = threadIdx.x;
  float part = 0.f;
#pragma unroll
  for (int kk = 0; kk < 2; ++kk) {
    int k = t + kk * 256;
    float sc = bn0_g[k] * rsqrtf(bn0_v[k] + EPS);
    part += (bn0_b[k] - bn0_m[k] * sc) * shW[k * 256 + n];
  }
#pragma unroll
  for (int m = 1; m < 64; m <<= 1) part += __shfl_xor(part, m);
  __shared__ float wsum[4];
  if ((t & 63) == 0) wsum[t >> 6] = part;
  __syncthreads();
  if (t == 0) {
    float bias = wsum[0] + wsum[1] + wsum[2] + wsum[3];
    float c1 = sh_g[n] * rsqrtf(sh_v[n] + EPS);
    wsf[C1_OFF + n] = c1;
    wsf[C2_OFF + n] = (bias - sh_m[n]) * c1 + sh_b[n];
#pragma unroll
    for (int s = 0; s < 3; ++s) {
      float a = st_g[s * 256 + n] * rsqrtf(st_v[s * 256 + n] + EPS);
      wsf[STC1_OFF + s * 256 + n] = a;
      wsf[STC2_OFF + s * 256 + n] = st_b[s * 256 + n] - st_m[s * 256 + n] * a;
    }
  }
}

// ---------------- main fused kernel ----------------
// 2048 blocks x 256 threads, 64 rows/block.
// Phase 0: stage x tile (64x512) to LDS bf16 with ADDRESS-SEQUENTIAL global reads
//          (full 2KB rows -> DRAM-page friendly; fixes the ~700 GB/s activate cap).
// Phase 1: A-frags from LDS, B-frags direct from L2-resident ws (1-step prefetch).
// Phase 2: 3 steps K=128 as before. sh-slab and reduce buffer alias the dead x slab.
__global__ __launch_bounds__(256) void tabnet_main(
    const float* __restrict__ x, const unsigned short* __restrict__ wsu,
    const float* __restrict__ wsf, const float* __restrict__ fW,
    const float* __restrict__ fb, float* __restrict__ out) {

  __shared__ __align__(16) unsigned short slab[64 * XSTRIDE];  // 66560 B
  unsigned short* xlds = slab;                  // phase 0/1: x tile, row-major stride 520
  unsigned short* shlds = slab;                 // phase 2: sh A-frags (first 16 KB, x dead)
  float* red = (float*)&slab[8192];             // final reduce (bytes 16384..17408)

  const int tid = threadIdx.x;
  const int wave = tid >> 6, lane = tid & 63;
  const int q = lane >> 4, l15 = lane & 15;
  const int wm = wave >> 1, wn = wave & 1;
  const long row0 = (long)blockIdx.x * 64;

  // ---- Phase 0: stage x rows sequentially ----
  {
    const float* xg = x + (row0 + wave * 16) * 512 + lane * 8;
#pragma unroll
    for (int half = 0; half < 2; ++half) {
      f32x4 t0[8], t1[8];
#pragma unroll
      for (int r = 0; r < 8; ++r) {
        const float* p = xg + (half * 8 + r) * 512;
        t0[r] = *(const f32x4*)p;
        t1[r] = *(const f32x4*)(p + 4);
      }
#pragma unroll
      for (int r = 0; r < 8; ++r) {
        int row = wave * 16 + half * 8 + r;
        *(short8*)&xlds[row * XSTRIDE + lane * 8] = cvt8(t0[r], t1[r]);
      }
    }
  }

  f32x4 acc[2][8];
#pragma unroll
  for (int a = 0; a < 2; ++a)
#pragma unroll
    for (int b = 0; b < 8; ++b) acc[a][b] = (f32x4)0.f;

  const int ncv = wn * 64 + l15;  // value col base (+nt*16); gate = +128

  __syncthreads();  // x staged

  // ---- Phase 1: K=512 as 16 steps; A from LDS, B from global (1-step prefetch) ----
  short8 bcur[8], bnxt[8];
  {
    const unsigned short* wb = wsu + q * 2048;
#pragma unroll
    for (int nt = 0; nt < 4; ++nt) {
      bcur[nt]     = *(const short8*)&wb[(ncv + nt * 16) * 8];
      bcur[nt + 4] = *(const short8*)&wb[(ncv + nt * 16 + 128) * 8];
    }
  }
#pragma unroll
  for (int st = 0; st < 16; ++st) {
    if (st < 15) {
      const unsigned short* wb = wsu + ((st + 1) * 4 + q) * 2048;
#pragma unroll
      for (int nt = 0; nt < 4; ++nt) {
        bnxt[nt]     = *(const short8*)&wb[(ncv + nt * 16) * 8];
        bnxt[nt + 4] = *(const short8*)&wb[(ncv + nt * 16 + 128) * 8];
      }
    }
    short8 af[2];
#pragma unroll
    for (int mt = 0; mt < 2; ++mt)
      af[mt] = *(const short8*)&xlds[(wm * 32 + mt * 16 + l15) * XSTRIDE + st * 32 + q * 8];
#pragma unroll
    for (int nt = 0; nt < 8; ++nt)
#pragma unroll
      for (int mt = 0; mt < 2; ++mt)
        acc[mt][nt] =
            __builtin_amdgcn_mfma_f32_16x16x32_bf16(af[mt], bcur[nt], acc[mt][nt], 0, 0, 0);
    if (st < 15) {
#pragma unroll
      for (int i = 0; i < 8; ++i) bcur[i] = bnxt[i];
    }
  }

  __syncthreads();  // x slab dead -> safe to overwrite with sh frags

  // ---- Phase-1 epilogue: BN + GLU in registers -> shlds (A-frag layout) ----
#pragma unroll
  for (int nt = 0; nt < 4; ++nt) {
    const int c = wn * 64 + nt * 16 + l15;  // sh col in [0,128)
    const float v1 = wsf[C1_OFF + c], v2 = wsf[C2_OFF + c];
    const float g1 = wsf[C1_OFF + c + 128], g2 = wsf[C2_OFF + c + 128];
#pragma unroll
    for (int mt = 0; mt < 2; ++mt)
#pragma unroll
      for (int r = 0; r < 4; ++r) {
        float y1 = acc[mt][nt][r] * v1 + v2;
        float y2 = acc[mt][nt + 4][r] * g1 + g2;
        float sg = __builtin_amdgcn_rcpf(1.f + __expf(-y2));
        int row = wm * 32 + mt * 16 + 4 * q + r;
        shlds[((c >> 3) * 64 + row) * 8 + (c & 7)] = f2bf(y1 * sg);
      }
  }
  __syncthreads();

  // ---- Phase 2: 3 steps, K=128; A from shlds, B direct from global (L2-hot) ----
  float agg[2][2][4];
#pragma unroll
  for (int a = 0; a < 2; ++a)
#pragma unroll
    for (int b = 0; b < 2; ++b)
#pragma unroll
      for (int r = 0; r < 4; ++r) agg[a][b][r] = 0.f;

  for (int s = 0; s < 3; ++s) {
    const unsigned short* wb = wsu + 131072 + s * 16384;
    f32x4 acc2[2][4];
#pragma unroll
    for (int a = 0; a < 2; ++a)
#pragma unroll
      for (int b = 0; b < 4; ++b) acc2[a][b] = (f32x4)0.f;
#pragma unroll
    for (int ks = 0; ks < 4; ++ks) {
      const int kq = ks * 4 + q;
      short8 bs[4];
#pragma unroll
      for (int j = 0; j < 2; ++j) {
        bs[j]     = *(const short8*)&wb[(kq * 128 + wn * 32 + j * 16 + l15) * 8];
        bs[j + 2] = *(const short8*)&wb[(kq * 128 + 64 + wn * 32 + j * 16 + l15) * 8];
      }
      short8 af[2];
#pragma unroll
      for (int mt = 0; mt < 2; ++mt)
        af[mt] = *(const short8*)&shlds[(kq * 64 + wm * 32 + mt * 16 + l15) * 8];
#pragma unroll
      for (int j = 0; j < 4; ++j)
#pragma unroll
        for (int mt = 0; mt < 2; ++mt)
          acc2[mt][j] =
              __builtin_amdgcn_mfma_f32_16x16x32_bf16(af[mt], bs[j], acc2[mt][j], 0, 0, 0);
    }
#pragma unroll
    for (int j = 0; j < 2; ++j) {
      const int n1 = wn * 32 + j * 16 + l15;  // value col in [0,64)
      const float a1 = wsf[STC1_OFF + s * 256 + n1], b1 = wsf[STC2_OFF + s * 256 + n1];
      const float a2 = wsf[STC1_OFF + s * 256 + n1 + 128], b2 = wsf[STC2_OFF + s * 256 + n1 + 128];
#pragma unroll
      for (int mt = 0; mt < 2; ++mt)
#pragma unroll
        for (int r = 0; r < 4; ++r) {
          float y1 = acc2[mt][j][r] * a1 + b1;
          float y2 = acc2[mt][j + 2][r] * a2 + b2;
          agg[mt][j][r] += y1 * __builtin_amdgcn_rcpf(1.f + __expf(-y2));
        }
    }
  }
  __syncthreads();  // sh reads done; red region free

  // ---- Final: out = agg @ fW + fb ----
  {
#pragma unroll
    for (int mt = 0; mt < 2; ++mt)
#pragma unroll
      for (int r = 0; r < 4; ++r) {
        float p0 = 0.f, p1 = 0.f;
#pragma unroll
        for (int j = 0; j < 2; ++j) {
          const int c = wn * 32 + j * 16 + l15;
          p0 += agg[mt][j][r] * fW[c * 2];
          p1 += agg[mt][j][r] * fW[c * 2 + 1];
        }
#pragma unroll
        for (int m = 1; m < 16; m <<= 1) {
          p0 += __shfl_xor(p0, m);
          p1 += __shfl_xor(p1, m);
        }
        if (l15 == 0) {
          int row = wm * 32 + mt * 16 + 4 * q + r;
          red[row * 4 + 0 * 2 + wn] = p0;
          red[row * 4 + 1 * 2 + wn] = p1;
        }
      }
  }
  __syncthreads();
  if (tid < 128) {
    int row = tid >> 1, o = tid & 1;
    out[(row0 + row) * 2 + o] = fb[o] + red[row * 4 + o * 2 + 0] + red[row * 4 + o * 2 + 1];
  }
}

extern "C" void kernel_launch(void* const* d_in, const int* in_sizes, int n_in,
                              void* d_out, int out_size, void* d_ws, size_t ws_size,
                              hipStream_t stream) {
  const float* x     = (const float*)d_in[0];
  const float* bn0_g = (const float*)d_in[1];
  const float* bn0_b = (const float*)d_in[2];
  const float* bn0_m = (const float*)d_in[3];
  const float* bn0_v = (const float*)d_in[4];
  const float* shW   = (const float*)d_in[5];
  const float* sh_g  = (const float*)d_in[6];
  const float* sh_b  = (const float*)d_in[7];
  const float* sh_m  = (const float*)d_in[8];
  const float* sh_v  = (const float*)d_in[9];
  const float* stW   = (const float*)d_in[10];
  const float* st_g  = (const float*)d_in[11];
  const float* st_b  = (const float*)d_in[12];
  const float* st_m  = (const float*)d_in[13];
  const float* st_v  = (const float*)d_in[14];
  // d_in[15..19] = atW, at_g, at_b, at_m, at_v : dead code (never feeds output)
  const float* fW    = (const float*)d_in[20];
  const float* fb    = (const float*)d_in[21];

  unsigned short* wsu = (unsigned short*)d_ws;
  float* wsf = (float*)d_ws;

  prep_w<<<88, 256, 0, stream>>>(shW, stW, bn0_g, bn0_v, wsu);
  prep_b<<<256, 256, 0, stream>>>(shW, bn0_g, bn0_b, bn0_m, bn0_v, sh_g, sh_b, sh_m,
                                  sh_v, st_g, st_b, st_m, st_v, wsf);
  tabnet_main<<<2048, 256, 0, stream>>>(x, wsu, wsf, fW, fb, (float*)d_out);
}